// Round 11
// baseline (108.105 us; speedup 1.0000x reference)
//
#include <hip/hip_runtime.h>
#include <hip/hip_bf16.h>
#include <math.h>

#define BB 4
#define CI 64
#define CO 64
#define HH 96
#define WW 96
#define HW (HH*WW)      // 9216
#define K2 9
#define PADC 1

// 4x4-px tiles; strips of 3 stacked tiles per block
#define TW 4
#define TH 4
#define TPXT 16
#define TBX (WW/TW)         // 24 tile-cols
#define TBY (HH/TH)         // 24 tile-rows
#define SLEN 3              // tiles per strip
#define GRID 768            // 96 cols-halves x 8 strips -> 3 blocks/CU

// LDS ring window: 16 rows x 16 cols, record stride 35 dwords (odd -> conflict-free)
#define WC 16
#define SREC 70
#define NSLOT (16*WC)       // 256

typedef __attribute__((ext_vector_type(8))) short short8;
typedef __attribute__((ext_vector_type(4))) float float4v;
typedef __attribute__((ext_vector_type(4))) unsigned int uint4v;

#define WF_USHORTS (18*64*32)
#define MWF_USHORTS (18*16*32)

__device__ __forceinline__ short f2bf(float f) {
    unsigned int u = __float_as_uint(f);
    u = (u + 0x7fffu + ((u >> 16) & 1u)) >> 16;   // RNE
    return (short)u;
}
__device__ __forceinline__ unsigned int pkbf(float lo, float hi) {
    float2 f; f.x = lo; f.y = hi;
    union { __hip_bfloat162 h; unsigned int u; } z;
    z.h = __float22bfloat162_rn(f);               // v_cvt_pk_bf16_f32
    return z.u;
}

// ---------------- prep: weight pack only ----------------
__global__ __launch_bounds__(256) void pack_kernel(const float* __restrict__ wgt,
                                                   const float* __restrict__ mw,
                                                   unsigned short* __restrict__ Wf,
                                                   unsigned short* __restrict__ MWf) {
    int i = blockIdx.x * 256 + threadIdx.x;
    if (i < WF_USHORTS) {
        int frag = i >> 11;
        int o = (i >> 5) & 63;
        int tt = i & 31;
        int k = frag >> 1, cc = frag & 1;
        int c = cc * 32 + tt;
        Wf[i] = (unsigned short)f2bf(wgt[o * 576 + c * 9 + k]);
    } else if (i < WF_USHORTS + MWF_USHORTS) {
        int e = i - WF_USHORTS;
        int frag = e >> 9;
        int m = (e >> 5) & 15;
        int tt = e & 31;
        int q = frag >> 1, cc = frag & 1;
        int c = cc * 32 + tt;
        MWf[e] = (m < 9) ? (unsigned short)f2bf(mw[m * 576 + c * 9 + q]) : 0;
    }
}

// ---------------- fused ----------------
struct SmemT {
    unsigned short win[NSLOT * SREC];   // 35,840 B (ring, live across tiles)
    float mred[2][2][K2][TPXT];         // 2,304 B
    int   idx[K2][4][TPXT];             // 2,304 B
    float w[K2][4][TPXT];               // 2,304 B
    float part[2][16][64];              // 8,192 B
};                                      // 50,944 B -> 3 blocks/CU

__device__ __forceinline__ uint4v ld_win4(const unsigned int* w32, int dw) {
    uint4v z;
    z[0] = w32[dw + 0]; z[1] = w32[dw + 1];
    z[2] = w32[dw + 2]; z[3] = w32[dw + 3];
    return z;
}
__device__ __forceinline__ short8 ld_win8(const unsigned int* w32, int dw) {
    union { uint4v u; short8 s; } z;
    z.u = ld_win4(w32, dw);
    return z.s;
}

__device__ __forceinline__ void stage_load(const float* __restrict__ xb, int label,
                                           int chp, int c0c, float4v* a, float4v* bq) {
    int row = min(max(label, 0), HH - 1);
    const float* s0 = xb + (size_t)(2 * chp) * HW + row * WW;
    const float* s1 = s0 + HW;
    if (c0c >= 0 && c0c + 3 < WW) {
        *a = *(const float4v*)(s0 + c0c);
        *bq = *(const float4v*)(s1 + c0c);
    } else {
        #pragma unroll
        for (int j = 0; j < 4; j++) {
            int cc2 = min(max(c0c + j, 0), WW - 1);
            (*a)[j] = s0[cc2]; (*bq)[j] = s1[cc2];
        }
    }
}
__device__ __forceinline__ void stage_write(unsigned int* w32, int label, int chp,
                                            int c4, float4v a, float4v bq) {
    int rslot = (label & 15) * WC;
    #pragma unroll
    for (int j = 0; j < 4; j++)
        w32[(rslot + c4 * 4 + j) * 35 + chp] = pkbf(a[j], bq[j]);
}

template<int KB, int KE>
__device__ __forceinline__ void run_strip(SmemT& sm, int t, int wv, int ch, int tg,
                                          const float* __restrict__ x,
                                          const float* __restrict__ off,
                                          const float* __restrict__ mbias,
                                          const unsigned short* __restrict__ Wf,
                                          const unsigned short* __restrict__ MWf,
                                          float* __restrict__ out, int bid) {
    constexpr int NK = KE - KB;
    int lane = t & 63;
    int n = lane & 15, quad = lane >> 4;
    unsigned int* w32 = (unsigned int*)sm.win;
    const unsigned int* w32c = (const unsigned int*)sm.win;

    // strip decode with XCD-batch affinity [R3 verified]
    int g = bid & 7, r = bid >> 3;      // r in [0,96)
    int b = g & 3, txh = g >> 2;
    int col = r >> 3, s = r & 7;
    int tx = txh * 12 + col;
    int ty0 = s * SLEN;
    int w0 = tx * TW;
    int wc0 = w0 - 4;
    const float* xb = x + (size_t)b * CI * HW;

    // ---- one-time register A-frags [R7 verified] ----
    short8 wA[NK][4];
    short8 mA[NK];
    #pragma unroll
    for (int kk = 0; kk < NK; kk++) {
        int k = KB + kk;
        const unsigned short* wp = Wf + (size_t)((k * 2 + ch) * 64) * 32 + quad * 8;
        #pragma unroll
        for (int ss = 0; ss < 4; ss++)
            wA[kk][ss] = *(const short8*)(wp + (ss * 16 + n) * 32);
        mA[kk] = *(const short8*)(MWf + ((size_t)((k * 2 + ch) * 16 + n)) * 32 + quad * 8);
    }

    int ly = n >> 2, lx = n & 3;
    int cbase_dw = ch * 16 + quad * 4;

    // ---- prologue: full 13-row window stage + tile-0 off prefetch ----
    for (int e = t; e < 13 * 128; e += 256) {
        int ri = e >> 7, chp = (e >> 2) & 31, c4 = e & 3;
        float4v a, bq;
        stage_load(xb, ty0 * TH - 4 + ri, chp, wc0 + c4 * 4, &a, &bq);
        stage_write(w32, ty0 * TH - 4 + ri, chp, c4, a, bq);
    }
    bool bm = t < K2 * TPXT;
    int km = t >> 4, pem = t & 15;
    float mbr = 0.f;
    size_t offy_base = ((size_t)b * 2 * K2 + 2 * km) * HW;
    size_t offx_base = offy_base + HW;
    float poy = 0.f, pox = 0.f;
    if (bm) {
        mbr = mbias[km];
        int p = (ty0 * TH + (pem >> 2)) * WW + w0 + (pem & 3);
        poy = off[offy_base + p];
        pox = off[offx_base + p];
    }

    for (int j = 0; j < SLEN; j++) {
        int h0 = (ty0 + j) * TH;
        int h = h0 + ly, wcc = w0 + lx;
        __syncthreads();   // staged rows visible

        // ---- issue next-tile prefetches (regs; consumed at loop bottom) ----
        float4v pa0, pb0, pa1, pb1;
        float noy = 0.f, nox = 0.f;
        bool hn = (j + 1 < SLEN);
        if (hn) {
            int e1 = t + 256;
            stage_load(xb, h0 + 9 + (t >> 7), (t >> 2) & 31, wc0 + (t & 3) * 4, &pa0, &pb0);
            stage_load(xb, h0 + 9 + (e1 >> 7), (e1 >> 2) & 31, wc0 + (e1 & 3) * 4, &pa1, &pb1);
            if (bm) {
                int p = (h0 + 4 + (pem >> 2)) * WW + w0 + (pem & 3);
                noy = off[offy_base + p];
                nox = off[offx_base + p];
            }
        }

        // ---- phase A: mask-conv partials via MFMA (window reads) ----
        {
            float4v macc = {0.f, 0.f, 0.f, 0.f};
            #pragma unroll
            for (int kk = 0; kk < NK; kk++) {
                int q = KB + kk;
                int hh = h + q / 3 - 1, ww2 = wcc + q % 3 - 1;
                bool valid = (hh >= 0) && (hh < HH) && (ww2 >= 0) && (ww2 < WW);
                short8 bfrag = {0, 0, 0, 0, 0, 0, 0, 0};
                if (valid) {
                    int slot = (hh & 15) * WC + (ww2 - wc0);
                    bfrag = ld_win8(w32c, slot * 35 + cbase_dw);
                }
                macc = __builtin_amdgcn_mfma_f32_16x16x32_bf16(mA[kk], bfrag, macc, 0, 0, 0);
            }
            #pragma unroll
            for (int rr = 0; rr < 4; rr++) {
                int row = quad * 4 + rr;
                if (row < 9) sm.mred[ch][tg][row][n] = macc[rr];
            }
        }
        __syncthreads();

        // ---- phase B: sampling metadata (prefetched off) ----
        if (bm) {
            int ph = h0 + (pem >> 2), pw = w0 + (pem & 3);
            float sl = sm.mred[0][0][km][pem] + sm.mred[0][1][km][pem] +
                       sm.mred[1][0][km][pem] + sm.mred[1][1][km][pem] + mbr;
            float m = 1.f / (1.f + expf(-sl));
            float py  = (float)(ph - PADC + km / 3) + poy;
            float pxf = (float)(pw - PADC + km % 3) + pox;
            float y0f = floorf(py), x0f = floorf(pxf);
            float wy = py - y0f, wx = pxf - x0f;
            int y0 = (int)y0f, x0 = (int)x0f;
            int y1 = y0 + 1, x1 = x0 + 1;
            int y0c = min(max(y0, 0), HH - 1), y1c = min(max(y1, 0), HH - 1);
            int x0c = min(max(x0, 0), WW - 1), x1c = min(max(x1, 0), WW - 1);
            bool vy0 = (y0 >= 0) && (y0 < HH), vy1 = (y1 >= 0) && (y1 < HH);
            bool vx0 = (x0 >= 0) && (x0 < WW), vx1 = (x1 >= 0) && (x1 < WW);
            float w00 = (1.f - wy) * (1.f - wx) * m; if (!(vy0 && vx0)) w00 = 0.f;
            float w01 = (1.f - wy) * wx * m;         if (!(vy0 && vx1)) w01 = 0.f;
            float w10 = wy * (1.f - wx) * m;         if (!(vy1 && vx0)) w10 = 0.f;
            float w11 = wy * wx * m;                 if (!(vy1 && vx1)) w11 = 0.f;
            sm.idx[km][0][pem] = (y0c << 16) | x0c;
            sm.idx[km][1][pem] = (y0c << 16) | x1c;
            sm.idx[km][2][pem] = (y1c << 16) | x0c;
            sm.idx[km][3][pem] = (y1c << 16) | x1c;
            sm.w[km][0][pem] = w00; sm.w[km][1][pem] = w01;
            sm.w[km][2][pem] = w10; sm.w[km][3][pem] = w11;
        }
        __syncthreads();

        // ---- phase C: window gathers + blend + MFMA ----
        float4v acc0 = {0.f, 0.f, 0.f, 0.f};
        float4v acc1 = {0.f, 0.f, 0.f, 0.f};
        float4v acc2 = {0.f, 0.f, 0.f, 0.f};
        float4v acc3 = {0.f, 0.f, 0.f, 0.f};
        const float* xfb = xb + (size_t)(ch * 32 + quad * 8) * HW;

        #pragma unroll
        for (int kk = 0; kk < NK; kk++) {
            int k = KB + kk;
            uint4v U[4];
            #pragma unroll
            for (int cor = 0; cor < 4; cor++) {
                int yx = sm.idx[k][cor][n];
                int yy = yx >> 16, xx = yx & 0xffff;
                bool inw = (yy >= h0 - 4) && (yy <= h0 + 8) &&
                           (xx >= wc0) && (xx <= wc0 + 15);
                uint4v u;
                if (inw) {
                    int slot = (yy & 15) * WC + (xx - wc0);
                    u = ld_win4(w32c, slot * 35 + cbase_dw);
                } else {
                    const float* fs = xfb + yy * WW + xx;
                    #pragma unroll
                    for (int dd = 0; dd < 4; dd++)
                        u[dd] = pkbf(fs[(size_t)(2 * dd) * HW], fs[(size_t)(2 * dd + 1) * HW]);
                }
                U[cor] = u;
            }
            float w0v = sm.w[k][0][n], w1v = sm.w[k][1][n];
            float w2v = sm.w[k][2][n], w3v = sm.w[k][3][n];
            union { unsigned int u[4]; short8 s; } bf;
            #pragma unroll
            for (int dd = 0; dd < 4; dd++) {
                float lo = __uint_as_float(U[0][dd] << 16) * w0v
                         + __uint_as_float(U[1][dd] << 16) * w1v
                         + __uint_as_float(U[2][dd] << 16) * w2v
                         + __uint_as_float(U[3][dd] << 16) * w3v;
                float hi = __uint_as_float(U[0][dd] & 0xffff0000u) * w0v
                         + __uint_as_float(U[1][dd] & 0xffff0000u) * w1v
                         + __uint_as_float(U[2][dd] & 0xffff0000u) * w2v
                         + __uint_as_float(U[3][dd] & 0xffff0000u) * w3v;
                bf.u[dd] = pkbf(lo, hi);
            }
            acc0 = __builtin_amdgcn_mfma_f32_16x16x32_bf16(wA[kk][0], bf.s, acc0, 0, 0, 0);
            acc1 = __builtin_amdgcn_mfma_f32_16x16x32_bf16(wA[kk][1], bf.s, acc1, 0, 0, 0);
            acc2 = __builtin_amdgcn_mfma_f32_16x16x32_bf16(wA[kk][2], bf.s, acc2, 0, 0, 0);
            acc3 = __builtin_amdgcn_mfma_f32_16x16x32_bf16(wA[kk][3], bf.s, acc3, 0, 0, 0);
        }

        // ---- two-round cross-wave reduce (part[2]) + epilogue ----
        if (wv >= 2) {
            #pragma unroll
            for (int rr = 0; rr < 4; rr++) {
                sm.part[wv - 2][0 * 4 + rr][lane] = acc0[rr];
                sm.part[wv - 2][1 * 4 + rr][lane] = acc1[rr];
                sm.part[wv - 2][2 * 4 + rr][lane] = acc2[rr];
                sm.part[wv - 2][3 * 4 + rr][lane] = acc3[rr];
            }
        }
        __syncthreads();
        if (wv == 1) {
            #pragma unroll
            for (int rr = 0; rr < 4; rr++) {
                acc0[rr] += sm.part[1][0 * 4 + rr][lane];
                acc1[rr] += sm.part[1][1 * 4 + rr][lane];
                acc2[rr] += sm.part[1][2 * 4 + rr][lane];
                acc3[rr] += sm.part[1][3 * 4 + rr][lane];
            }
            #pragma unroll
            for (int rr = 0; rr < 4; rr++) {
                sm.part[1][0 * 4 + rr][lane] = acc0[rr];
                sm.part[1][1 * 4 + rr][lane] = acc1[rr];
                sm.part[1][2 * 4 + rr][lane] = acc2[rr];
                sm.part[1][3 * 4 + rr][lane] = acc3[rr];
            }
        }
        if (wv == 0) {
            #pragma unroll
            for (int rr = 0; rr < 4; rr++) {
                acc0[rr] += sm.part[0][0 * 4 + rr][lane];
                acc1[rr] += sm.part[0][1 * 4 + rr][lane];
                acc2[rr] += sm.part[0][2 * 4 + rr][lane];
                acc3[rr] += sm.part[0][3 * 4 + rr][lane];
            }
        }
        __syncthreads();
        if (wv == 0) {
            float* ob = out + (size_t)b * CO * HW + h * WW + wcc;
            #pragma unroll
            for (int rr = 0; rr < 4; rr++) {
                ob[(size_t)(0 * 16 + quad * 4 + rr) * HW] = acc0[rr] + sm.part[1][0 * 4 + rr][lane];
                ob[(size_t)(1 * 16 + quad * 4 + rr) * HW] = acc1[rr] + sm.part[1][1 * 4 + rr][lane];
                ob[(size_t)(2 * 16 + quad * 4 + rr) * HW] = acc2[rr] + sm.part[1][2 * 4 + rr][lane];
                ob[(size_t)(3 * 16 + quad * 4 + rr) * HW] = acc3[rr] + sm.part[1][3 * 4 + rr][lane];
            }
        }

        // ---- loop bottom: commit prefetched rows to ring; rotate off regs ----
        if (hn) {
            int e1 = t + 256;
            stage_write(w32, h0 + 9 + (t >> 7), (t >> 2) & 31, t & 3, pa0, pb0);
            stage_write(w32, h0 + 9 + (e1 >> 7), (e1 >> 2) & 31, e1 & 3, pa1, pb1);
            poy = noy; pox = nox;
        }
    }
}

__global__ __launch_bounds__(256, 3) void fused_kernel(const float* __restrict__ x,
                                                       const float* __restrict__ off,
                                                       const float* __restrict__ mbias,
                                                       const unsigned short* __restrict__ Wf,
                                                       const unsigned short* __restrict__ MWf,
                                                       float* __restrict__ out) {
    __shared__ SmemT sm;
    int t = threadIdx.x;
    int wv = t >> 6;
    int ch = wv & 1, tg = wv >> 1;
    if (tg == 0)
        run_strip<0, 5>(sm, t, wv, ch, tg, x, off, mbias, Wf, MWf, out, blockIdx.x);
    else
        run_strip<5, 9>(sm, t, wv, ch, tg, x, off, mbias, Wf, MWf, out, blockIdx.x);
}

extern "C" void kernel_launch(void* const* d_in, const int* in_sizes, int n_in,
                              void* d_out, int out_size, void* d_ws, size_t ws_size,
                              hipStream_t stream) {
    const float* x   = (const float*)d_in[0];
    const float* off = (const float*)d_in[1];
    const float* wgt = (const float*)d_in[2];
    const float* mw  = (const float*)d_in[3];
    const float* mb  = (const float*)d_in[4];
    float* out = (float*)d_out;

    unsigned short* Wf  = (unsigned short*)d_ws;
    unsigned short* MWf = Wf + WF_USHORTS;

    hipLaunchKernelGGL(pack_kernel, dim3((WF_USHORTS + MWF_USHORTS + 255) / 256), dim3(256),
                       0, stream, wgt, mw, Wf, MWf);
    hipLaunchKernelGGL(fused_kernel, dim3(GRID), dim3(256), 0, stream,
                       x, off, mb, Wf, MWf, out);
}

// Round 12
// 105.719 us; speedup vs baseline: 1.0226x; 1.0226x over previous
//
#include <hip/hip_runtime.h>
#include <hip/hip_bf16.h>
#include <math.h>

#define BB 4
#define CI 64
#define CO 64
#define HH 96
#define WW 96
#define HW (HH*WW)      // 9216
#define K2 9
#define PADC 1

// 4x4-px tiles; strips of 5 stacked tiles per block (last strip 4)
#define TW 4
#define TH 4
#define TPXT 16
#define TBX (WW/TW)         // 24
#define TBY (HH/TH)         // 24
#define GRID 480            // 8 g x (12 cols x 5 strips) -> 2 blocks/CU

// LDS ring window: 16 rows x 16 cols, record stride 35 dwords (odd -> spread banks)
#define WC 16
#define SREC 70
#define NSLOT (16*WC)       // 256

typedef __attribute__((ext_vector_type(8))) short short8;
typedef __attribute__((ext_vector_type(4))) float float4v;
typedef __attribute__((ext_vector_type(4))) unsigned int uint4v;

#define WF_USHORTS (18*64*32)
#define MWF_USHORTS (18*16*32)

__device__ __forceinline__ short f2bf(float f) {
    unsigned int u = __float_as_uint(f);
    u = (u + 0x7fffu + ((u >> 16) & 1u)) >> 16;   // RNE
    return (short)u;
}
__device__ __forceinline__ unsigned int pkbf(float lo, float hi) {
    float2 f; f.x = lo; f.y = hi;
    union { __hip_bfloat162 h; unsigned int u; } z;
    z.h = __float22bfloat162_rn(f);               // v_cvt_pk_bf16_f32
    return z.u;
}

// ---------------- prep: weight pack only ----------------
__global__ __launch_bounds__(256) void pack_kernel(const float* __restrict__ wgt,
                                                   const float* __restrict__ mw,
                                                   unsigned short* __restrict__ Wf,
                                                   unsigned short* __restrict__ MWf) {
    int i = blockIdx.x * 256 + threadIdx.x;
    if (i < WF_USHORTS) {
        int frag = i >> 11;
        int o = (i >> 5) & 63;
        int tt = i & 31;
        int k = frag >> 1, cc = frag & 1;
        int c = cc * 32 + tt;
        Wf[i] = (unsigned short)f2bf(wgt[o * 576 + c * 9 + k]);
    } else if (i < WF_USHORTS + MWF_USHORTS) {
        int e = i - WF_USHORTS;
        int frag = e >> 9;
        int m = (e >> 5) & 15;
        int tt = e & 31;
        int q = frag >> 1, cc = frag & 1;
        int c = cc * 32 + tt;
        MWf[e] = (m < 9) ? (unsigned short)f2bf(mw[m * 576 + c * 9 + q]) : 0;
    }
}

// ---------------- fused ----------------
struct SmemT {
    unsigned short win[NSLOT * SREC];   // 35,840 B (ring, live across tiles)
    float mred[2][2][K2][TPXT];         // 2,304 B
    int   idx[K2][4][TPXT];             // 2,304 B
    float w[K2][4][TPXT];               // 2,304 B
    float part[2][3][16][64];           // 24,576 B (double-buffered)
};                                      // 67,328 B -> 2 blocks/CU

__device__ __forceinline__ uint4v ld_win4(const unsigned int* w32, int dw) {
    uint4v z;
    z[0] = w32[dw + 0]; z[1] = w32[dw + 1];
    z[2] = w32[dw + 2]; z[3] = w32[dw + 3];
    return z;
}
__device__ __forceinline__ short8 ld_win8(const unsigned int* w32, int dw) {
    union { uint4v u; short8 s; } z;
    z.u = ld_win4(w32, dw);
    return z.s;
}

__device__ __forceinline__ void stage_load(const float* __restrict__ xb, int label,
                                           int chp, int c0c, float4v* a, float4v* bq) {
    int row = min(max(label, 0), HH - 1);
    const float* s0 = xb + (size_t)(2 * chp) * HW + row * WW;
    const float* s1 = s0 + HW;
    if (c0c >= 0 && c0c + 3 < WW) {
        *a = *(const float4v*)(s0 + c0c);
        *bq = *(const float4v*)(s1 + c0c);
    } else {
        #pragma unroll
        for (int j = 0; j < 4; j++) {
            int cc2 = min(max(c0c + j, 0), WW - 1);
            (*a)[j] = s0[cc2]; (*bq)[j] = s1[cc2];
        }
    }
}
__device__ __forceinline__ void stage_write(unsigned int* w32, int label, int chp,
                                            int c4, float4v a, float4v bq) {
    int rslot = (label & 15) * WC;
    #pragma unroll
    for (int j = 0; j < 4; j++)
        w32[(rslot + c4 * 4 + j) * 35 + chp] = pkbf(a[j], bq[j]);
}

template<int KB, int KE>
__device__ __forceinline__ void run_strip(SmemT& sm, int t, int wv, int ch, int tg,
                                          const float* __restrict__ x,
                                          const float* __restrict__ off,
                                          const float* __restrict__ mbias,
                                          const unsigned short* __restrict__ Wf,
                                          const unsigned short* __restrict__ MWf,
                                          float* __restrict__ out, int bid) {
    constexpr int NK = KE - KB;
    int lane = t & 63;
    int n = lane & 15, quad = lane >> 4;
    unsigned int* w32 = (unsigned int*)sm.win;
    const unsigned int* w32c = (const unsigned int*)sm.win;

    // strip decode with XCD-batch affinity [R3 verified]
    int g = bid & 7, r = bid >> 3;      // r in [0,60)
    int b = g & 3, txh = g >> 2;
    int col = r / 5, s = r % 5;
    int tx = txh * 12 + col;
    int ty0 = (s < 4) ? s * 5 : 20;
    int len = (s < 4) ? 5 : 4;
    int w0 = tx * TW;
    int wc0 = w0 - 4;
    const float* xb = x + (size_t)b * CI * HW;

    // ---- one-time register A-frags [R7 verified] ----
    short8 wA[NK][4];
    short8 mA[NK];
    #pragma unroll
    for (int kk = 0; kk < NK; kk++) {
        int k = KB + kk;
        const unsigned short* wp = Wf + (size_t)((k * 2 + ch) * 64) * 32 + quad * 8;
        #pragma unroll
        for (int ss = 0; ss < 4; ss++)
            wA[kk][ss] = *(const short8*)(wp + (ss * 16 + n) * 32);
        mA[kk] = *(const short8*)(MWf + ((size_t)((k * 2 + ch) * 16 + n)) * 32 + quad * 8);
    }

    int ly = n >> 2, lx = n & 3;
    int cbase_dw = ch * 16 + quad * 4;

    // ---- prologue: full 13-row window stage + tile-0 off prefetch ----
    for (int e = t; e < 13 * 128; e += 256) {
        int ri = e >> 7, chp = (e >> 2) & 31, c4 = e & 3;
        float4v a, bq;
        stage_load(xb, ty0 * TH - 4 + ri, chp, wc0 + c4 * 4, &a, &bq);
        stage_write(w32, ty0 * TH - 4 + ri, chp, c4, a, bq);
    }
    bool bm = t < K2 * TPXT;
    int km = t >> 4, pem = t & 15;
    float mbr = 0.f;
    size_t offy_base = ((size_t)b * 2 * K2 + 2 * km) * HW;
    size_t offx_base = offy_base + HW;
    float poy = 0.f, pox = 0.f;
    if (bm) {
        mbr = mbias[km];
        int p = (ty0 * TH + (pem >> 2)) * WW + w0 + (pem & 3);
        poy = off[offy_base + p];
        pox = off[offx_base + p];
    }

    for (int j = 0; j < len; j++) {
        int h0 = (ty0 + j) * TH;
        int h = h0 + ly, wcc = w0 + lx;
        int pb = j & 1;
        __syncthreads();   // staged rows + prev part reads settled

        // ---- issue next-tile prefetches (regs; committed at loop bottom) ----
        float4v pa0, pb0, pa1, pb1;
        float noy = 0.f, nox = 0.f;
        bool hn = (j + 1 < len);
        if (hn) {
            int e1 = t + 256;
            stage_load(xb, h0 + 9 + (t >> 7), (t >> 2) & 31, wc0 + (t & 3) * 4, &pa0, &pb0);
            stage_load(xb, h0 + 9 + (e1 >> 7), (e1 >> 2) & 31, wc0 + (e1 & 3) * 4, &pa1, &pb1);
            if (bm) {
                int p = (h0 + 4 + (pem >> 2)) * WW + w0 + (pem & 3);
                noy = off[offy_base + p];
                nox = off[offx_base + p];
            }
        }

        // ---- phase A: mask-conv partials via MFMA (window reads) ----
        {
            float4v macc = {0.f, 0.f, 0.f, 0.f};
            #pragma unroll
            for (int kk = 0; kk < NK; kk++) {
                int q = KB + kk;
                int hh = h + q / 3 - 1, ww2 = wcc + q % 3 - 1;
                bool valid = (hh >= 0) && (hh < HH) && (ww2 >= 0) && (ww2 < WW);
                short8 bfrag = {0, 0, 0, 0, 0, 0, 0, 0};
                if (valid) {
                    int slot = (hh & 15) * WC + (ww2 - wc0);
                    bfrag = ld_win8(w32c, slot * 35 + cbase_dw);
                }
                macc = __builtin_amdgcn_mfma_f32_16x16x32_bf16(mA[kk], bfrag, macc, 0, 0, 0);
            }
            #pragma unroll
            for (int rr = 0; rr < 4; rr++) {
                int row = quad * 4 + rr;
                if (row < 9) sm.mred[ch][tg][row][n] = macc[rr];
            }
        }
        __syncthreads();

        // ---- phase B: sampling metadata (prefetched off) ----
        if (bm) {
            int ph = h0 + (pem >> 2), pw = w0 + (pem & 3);
            float sl = sm.mred[0][0][km][pem] + sm.mred[0][1][km][pem] +
                       sm.mred[1][0][km][pem] + sm.mred[1][1][km][pem] + mbr;
            float m = 1.f / (1.f + expf(-sl));
            float py  = (float)(ph - PADC + km / 3) + poy;
            float pxf = (float)(pw - PADC + km % 3) + pox;
            float y0f = floorf(py), x0f = floorf(pxf);
            float wy = py - y0f, wx = pxf - x0f;
            int y0 = (int)y0f, x0 = (int)x0f;
            int y1 = y0 + 1, x1 = x0 + 1;
            int y0c = min(max(y0, 0), HH - 1), y1c = min(max(y1, 0), HH - 1);
            int x0c = min(max(x0, 0), WW - 1), x1c = min(max(x1, 0), WW - 1);
            bool vy0 = (y0 >= 0) && (y0 < HH), vy1 = (y1 >= 0) && (y1 < HH);
            bool vx0 = (x0 >= 0) && (x0 < WW), vx1 = (x1 >= 0) && (x1 < WW);
            float w00 = (1.f - wy) * (1.f - wx) * m; if (!(vy0 && vx0)) w00 = 0.f;
            float w01 = (1.f - wy) * wx * m;         if (!(vy0 && vx1)) w01 = 0.f;
            float w10 = wy * (1.f - wx) * m;         if (!(vy1 && vx0)) w10 = 0.f;
            float w11 = wy * wx * m;                 if (!(vy1 && vx1)) w11 = 0.f;
            sm.idx[km][0][pem] = (y0c << 16) | x0c;
            sm.idx[km][1][pem] = (y0c << 16) | x1c;
            sm.idx[km][2][pem] = (y1c << 16) | x0c;
            sm.idx[km][3][pem] = (y1c << 16) | x1c;
            sm.w[km][0][pem] = w00; sm.w[km][1][pem] = w01;
            sm.w[km][2][pem] = w10; sm.w[km][3][pem] = w11;
        }
        __syncthreads();

        // ---- phase C: window gathers + blend + MFMA ----
        float4v acc0 = {0.f, 0.f, 0.f, 0.f};
        float4v acc1 = {0.f, 0.f, 0.f, 0.f};
        float4v acc2 = {0.f, 0.f, 0.f, 0.f};
        float4v acc3 = {0.f, 0.f, 0.f, 0.f};
        const float* xfb = xb + (size_t)(ch * 32 + quad * 8) * HW;

        #pragma unroll
        for (int kk = 0; kk < NK; kk++) {
            int k = KB + kk;
            uint4v U[4];
            #pragma unroll
            for (int cor = 0; cor < 4; cor++) {
                int yx = sm.idx[k][cor][n];
                int yy = yx >> 16, xx = yx & 0xffff;
                bool inw = (yy >= h0 - 4) && (yy <= h0 + 8) &&
                           (xx >= wc0) && (xx <= wc0 + 15);
                uint4v u;
                if (inw) {
                    int slot = (yy & 15) * WC + (xx - wc0);
                    u = ld_win4(w32c, slot * 35 + cbase_dw);
                } else {
                    const float* fs = xfb + yy * WW + xx;
                    #pragma unroll
                    for (int dd = 0; dd < 4; dd++)
                        u[dd] = pkbf(fs[(size_t)(2 * dd) * HW], fs[(size_t)(2 * dd + 1) * HW]);
                }
                U[cor] = u;
            }
            float w0v = sm.w[k][0][n], w1v = sm.w[k][1][n];
            float w2v = sm.w[k][2][n], w3v = sm.w[k][3][n];
            union { unsigned int u[4]; short8 s; } bf;
            #pragma unroll
            for (int dd = 0; dd < 4; dd++) {
                float lo = __uint_as_float(U[0][dd] << 16) * w0v
                         + __uint_as_float(U[1][dd] << 16) * w1v
                         + __uint_as_float(U[2][dd] << 16) * w2v
                         + __uint_as_float(U[3][dd] << 16) * w3v;
                float hi = __uint_as_float(U[0][dd] & 0xffff0000u) * w0v
                         + __uint_as_float(U[1][dd] & 0xffff0000u) * w1v
                         + __uint_as_float(U[2][dd] & 0xffff0000u) * w2v
                         + __uint_as_float(U[3][dd] & 0xffff0000u) * w3v;
                bf.u[dd] = pkbf(lo, hi);
            }
            acc0 = __builtin_amdgcn_mfma_f32_16x16x32_bf16(wA[kk][0], bf.s, acc0, 0, 0, 0);
            acc1 = __builtin_amdgcn_mfma_f32_16x16x32_bf16(wA[kk][1], bf.s, acc1, 0, 0, 0);
            acc2 = __builtin_amdgcn_mfma_f32_16x16x32_bf16(wA[kk][2], bf.s, acc2, 0, 0, 0);
            acc3 = __builtin_amdgcn_mfma_f32_16x16x32_bf16(wA[kk][3], bf.s, acc3, 0, 0, 0);
        }

        // ---- single-round cross-wave reduce (double-buffered part) ----
        if (wv != 0) {
            #pragma unroll
            for (int rr = 0; rr < 4; rr++) {
                sm.part[pb][wv - 1][0 * 4 + rr][lane] = acc0[rr];
                sm.part[pb][wv - 1][1 * 4 + rr][lane] = acc1[rr];
                sm.part[pb][wv - 1][2 * 4 + rr][lane] = acc2[rr];
                sm.part[pb][wv - 1][3 * 4 + rr][lane] = acc3[rr];
            }
        }
        __syncthreads();   // part visible; all window reads of tile j drained
        if (wv == 0) {
            float* ob = out + (size_t)b * CO * HW + h * WW + wcc;
            #pragma unroll
            for (int rr = 0; rr < 4; rr++) {
                int j0 = rr, j1 = 4 + rr, j2 = 8 + rr, j3 = 12 + rr;
                ob[(size_t)(0 * 16 + quad * 4 + rr) * HW] = acc0[rr] +
                    sm.part[pb][0][j0][lane] + sm.part[pb][1][j0][lane] + sm.part[pb][2][j0][lane];
                ob[(size_t)(1 * 16 + quad * 4 + rr) * HW] = acc1[rr] +
                    sm.part[pb][0][j1][lane] + sm.part[pb][1][j1][lane] + sm.part[pb][2][j1][lane];
                ob[(size_t)(2 * 16 + quad * 4 + rr) * HW] = acc2[rr] +
                    sm.part[pb][0][j2][lane] + sm.part[pb][1][j2][lane] + sm.part[pb][2][j2][lane];
                ob[(size_t)(3 * 16 + quad * 4 + rr) * HW] = acc3[rr] +
                    sm.part[pb][0][j3][lane] + sm.part[pb][1][j3][lane] + sm.part[pb][2][j3][lane];
            }
        }

        // ---- loop bottom: commit prefetched rows (disjoint ring slots) ----
        if (hn) {
            int e1 = t + 256;
            stage_write(w32, h0 + 9 + (t >> 7), (t >> 2) & 31, t & 3, pa0, pb0);
            stage_write(w32, h0 + 9 + (e1 >> 7), (e1 >> 2) & 31, e1 & 3, pa1, pb1);
            poy = noy; pox = nox;
        }
    }
}

__global__ __launch_bounds__(256, 2) void fused_kernel(const float* __restrict__ x,
                                                       const float* __restrict__ off,
                                                       const float* __restrict__ mbias,
                                                       const unsigned short* __restrict__ Wf,
                                                       const unsigned short* __restrict__ MWf,
                                                       float* __restrict__ out) {
    __shared__ SmemT sm;
    int t = threadIdx.x;
    int wv = t >> 6;
    int ch = wv & 1, tg = wv >> 1;
    if (tg == 0)
        run_strip<0, 5>(sm, t, wv, ch, tg, x, off, mbias, Wf, MWf, out, blockIdx.x);
    else
        run_strip<5, 9>(sm, t, wv, ch, tg, x, off, mbias, Wf, MWf, out, blockIdx.x);
}

extern "C" void kernel_launch(void* const* d_in, const int* in_sizes, int n_in,
                              void* d_out, int out_size, void* d_ws, size_t ws_size,
                              hipStream_t stream) {
    const float* x   = (const float*)d_in[0];
    const float* off = (const float*)d_in[1];
    const float* wgt = (const float*)d_in[2];
    const float* mw  = (const float*)d_in[3];
    const float* mb  = (const float*)d_in[4];
    float* out = (float*)d_out;

    unsigned short* Wf  = (unsigned short*)d_ws;
    unsigned short* MWf = Wf + WF_USHORTS;

    hipLaunchKernelGGL(pack_kernel, dim3((WF_USHORTS + MWF_USHORTS + 255) / 256), dim3(256),
                       0, stream, wgt, mw, Wf, MWf);
    hipLaunchKernelGGL(fused_kernel, dim3(GRID), dim3(256), 0, stream,
                       x, off, mb, Wf, MWf, out);
}